// Round 11
// baseline (27845.352 us; speedup 1.0000x reference)
//
#include <hip/hip_runtime.h>
#include <math.h>

// Problem constants (fixed by setup_inputs)
constexpr int U      = 128;   // UNITS
constexpr int G4     = 512;   // 4*U gate width
constexpr int NCls   = 10;    // classes
constexpr int TSTEPS = 1000;
constexpr int BATCH  = 256;
constexpr int CROWS  = 48;    // Wh0 rows cached in LDS (96 KB)

// ---------------------------------------------------------------------------
// Evidence ledger:
//  r0 naive per-use loads, 512 thr                15.7 ms
//  r1-r3 cross-barrier register streaming         29-30 ms
//  r4 per-use + 4 accs + LN-fold + 4 barriers      8.57 ms
//  r5 NB=4 batching (grid 64)                     17.1 ms
//  r6 1024 thr + partial-z + packed LDS cache      7.95 ms
//  r7 row-major dwordx4 weight streaming           7.09 ms   <- best
//  r8 16 float4 reg prefetch across barriers      15.5 ms (spill: cap=65536/thr)
//  r9 2-barrier wave-split, gates replicated x4    9.45 ms (replication VALU+LDS)
//  r10 (this kernel) -- infra failure, no data; resubmitted unchanged.
// Laws: (1) VGPR cap = 65536/blockDim (1024thr -> 64); demand above -> scratch.
//       (2) Overlap must not replicate work (r9).
// Structure = r7 skeleton, 3 barriers:
//   A-window: all waves matvec0 -> zuA (48 rows LDS-cached, 80 streamed)
//   B1; W2:  tid<128 gates0  ||  half-1 waves do the ENTIRE Wh1 x h1(t-1)
//            C-share (h1 crossed B1; 248 KB of port work overlays gates0)
//   B2; W3:  half-0 waves do Wx1 x gh0(t) -> zuB
//   B3; wave 0 ONLY: gates1(t) (2 units/lane) + FC + softmax + store, then
//       falls into A(t+1) with everyone else -- no 4th barrier; the 15 other
//       waves' phase-A port traffic hides wave 0's ~1.3 kcyc serial work.
//   +1-float4/thread loop-invariant register cache of each thread's first
//    phase-C row (16 KB/step off the port; demand ~58 < 64 cap).
// ---------------------------------------------------------------------------

__device__ __forceinline__ float sigm(float x) {
    return 1.0f / (1.0f + __expf(-x));
}

// k = time_gate(t, tau, s); floor-mod semantics matching jnp.mod
__device__ __forceinline__ float tgate(float t, float tau, float s) {
    float r = fmodf(t - s, tau);
    if (r < 0.0f) r += tau;
    const float phi = r / tau;
    return (phi < 0.025f) ? 40.0f * phi
         : (phi < 0.05f)  ? 2.0f - 40.0f * phi
         : 0.001f * phi;
}

// 4-row FMA block: ac.{x,y,z,w} are 4 output columns; hb broadcasts 4 rows.
#define ROW4(WP, I, HB) { \
    float4 w_; \
    w_ = (WP)[((I)+0)*128]; ac.x += (HB).x*w_.x; ac.y += (HB).x*w_.y; ac.z += (HB).x*w_.z; ac.w += (HB).x*w_.w; \
    w_ = (WP)[((I)+1)*128]; ac.x += (HB).y*w_.x; ac.y += (HB).y*w_.y; ac.z += (HB).y*w_.z; ac.w += (HB).y*w_.w; \
    w_ = (WP)[((I)+2)*128]; ac.x += (HB).z*w_.x; ac.y += (HB).z*w_.y; ac.z += (HB).z*w_.z; ac.w += (HB).z*w_.w; \
    w_ = (WP)[((I)+3)*128]; ac.x += (HB).w*w_.x; ac.y += (HB).w*w_.y; ac.z += (HB).w*w_.z; ac.w += (HB).w*w_.w; }

__global__ __launch_bounds__(1024, 1) void plstm_fused(
    const float* __restrict__ inputs,  // [B,T,3]
    const float* __restrict__ times,   // [B,T]
    const float* __restrict__ Wx0,     // [3,512]
    const float* __restrict__ Wh0,     // [128,512]
    const float* __restrict__ b0,      // [512]
    const float* __restrict__ tau0,    // [128]
    const float* __restrict__ s0,      // [128]
    const float* __restrict__ Wx1,     // [128,512]
    const float* __restrict__ Wh1,     // [128,512]
    const float* __restrict__ b1,      // [512]
    const float* __restrict__ tau1,    // [128]
    const float* __restrict__ s1,      // [128]
    const float* __restrict__ gamma_,  // [128]
    const float* __restrict__ beta_,   // [128]
    const float* __restrict__ Wfc,     // [128,10]
    const float* __restrict__ bfc,     // [10]
    float* __restrict__ out)           // [B,T,10]
{
    const int tid  = threadIdx.x;       // 0..1023
    const int lane = tid & 63;
    const int wv   = tid >> 6;          // wave 0..15
    const int c4   = tid & 127;         // column quad
    const int g    = tid >> 7;          // phase-A rowgroup 0..7 (16 rows)
    const int half = tid >> 9;          // 0: Wx1 side, 1: Wh1 side (phase C)
    const int rgC  = (tid >> 7) & 3;    // phase-C rowgroup (32 rows)
    const int b    = blockIdx.x;

    __shared__ __align__(16) float wh0c[CROWS * G4];   // 96 KB: Wh0 rows 0..47
    __shared__ __align__(16) float zuA[8 * G4];        // 16 KB layer-0 partials
    __shared__ __align__(16) float zuB[8 * G4];        // 16 KB layer-1 partials
    __shared__ __align__(16) float h0s[U];             // h0 state
    __shared__ __align__(16) float ghu[2 * U];         // [0..127]=gamma*h0, [128..255]=h1
    __shared__ __align__(16) float b0s[G4], b1s[G4], Ps[G4], Qs[G4];
    __shared__ __align__(16) float wx0s[3 * G4];
    __shared__ __align__(16) float wfcs[U * 11];       // stride 11
    __shared__ float bfcs[NCls];
    __shared__ float red[4];                           // {sum0,sq0,sum1,sq1}
    __shared__ float gms[U], bts[U];

    // ---- prologue: stage everything ----
    if (tid < U) { gms[tid] = gamma_[tid]; bts[tid] = beta_[tid];
                   h0s[tid] = 0.f; ghu[tid] = 0.f; ghu[U + tid] = 0.f; }
    {   // Wh0 rows 0..47 contiguous: 6144 float4 = 6 per thread
        float4* dst = reinterpret_cast<float4*>(wh0c);
        const float4* src = reinterpret_cast<const float4*>(Wh0);
        #pragma unroll
        for (int i = 0; i < 6; ++i) dst[tid + i * 1024] = src[tid + i * 1024];
    }
    if (tid < G4) { b0s[tid] = b0[tid]; b1s[tid] = b1[tid]; }
    for (int i = tid; i < 3 * G4; i += 1024) wx0s[i] = Wx0[i];
    for (int i = tid; i < U * NCls; i += 1024) {
        const int u = i / NCls, c = i - u * NCls;
        wfcs[u * 11 + c] = Wfc[i];
    }
    if (tid < NCls) bfcs[tid] = bfc[tid];
    __syncthreads();

    // ---- LN fold constants: P[j]=sum beta[u]*Wx1[u][j], Q[j]=sum gamma[u]*Wx1[u][j]
    if (tid < G4) {
        float P = 0.f, Q = 0.f;
        #pragma unroll 8
        for (int u = 0; u < U; ++u) {
            const float w = Wx1[u * G4 + tid];
            Q += gms[u] * w;
            P += bts[u] * w;
        }
        Ps[tid] = P; Qs[tid] = Q;
    }

    // ---- gate parameters ----
    float tau0r = 0.f, s0r = 0.f, gr = 0.f;          // gates0 (tid<128)
    if (tid < U) { tau0r = tau0[tid]; s0r = s0[tid]; gr = gms[tid]; }
    float tau1A = 0.f, s1A = 0.f, tau1B = 0.f, s1B = 0.f;  // gates1 (wave 0)
    if (wv == 0) { tau1A = tau1[lane]; s1A = s1[lane];
                   tau1B = tau1[lane + 64]; s1B = s1[lane + 64]; }
    float c0r = 0.f, h0r = 0.f;                       // layer-0 state (tid<128)
    float c1A = 0.f, h1A = 0.f, c1B = 0.f, h1B = 0.f; // layer-1 state (wave 0)

    // ---- loop-invariant bases ----
    const float4* __restrict__ wpA  =
        reinterpret_cast<const float4*>(Wh0) + g * 16 * 128 + c4;       // g>=3 stream
    const float4* __restrict__ wpAc =
        reinterpret_cast<const float4*>(wh0c) + g * 16 * 128 + c4;      // g<3 cached
    const float4* __restrict__ wpC  =
        reinterpret_cast<const float4*>(half ? Wh1 : Wx1) + rgC * 32 * 128 + c4;
    const float* __restrict__ hvC = ghu + half * U + rgC * 32;          // broadcast base
    const float4 pc = wpC[0];     // register-cached first C-row (loop-invariant)

    const float* __restrict__ xp = inputs + (size_t)b * TSTEPS * 3;
    const float* __restrict__ tp = times  + (size_t)b * TSTEPS;
    float*       __restrict__ op = out    + (size_t)b * TSTEPS * NCls;

    float xa0 = xp[0], xa1 = xp[1], xa2 = xp[2], tva = tp[0];

    __syncthreads();

    for (int t = 0; t < TSTEPS; ++t) {
        const float x0 = xa0, x1 = xa1, x2 = xa2, tv = tva;
        const int tn = (t + 1 < TSTEPS) ? t + 1 : t;
        xa0 = xp[tn*3+0]; xa1 = xp[tn*3+1]; xa2 = xp[tn*3+2]; tva = tp[tn];

        // ---- phase A: matvec0 -> zuA (rows g<3 cached, g>=3 streamed) ----
        {
            float4 ac = make_float4(0.f, 0.f, 0.f, 0.f);
            const float4* wp = (g < 3) ? wpAc : wpA;
            #pragma unroll
            for (int i = 0; i < 16; i += 4) {
                const float4 hb = *reinterpret_cast<const float4*>(&h0s[g * 16 + i]);
                ROW4(wp, i, hb);
            }
            *reinterpret_cast<float4*>(&zuA[g * G4 + 4 * c4]) = ac;
        }
        __syncthreads();                                   // ===== B1 =====

        // ---- W2: gates0 (tid<128)  ||  C-half1: Wh1 x h1(t-1) -> zuB[4..7] ----
        if (tid < U) {
            const int u = tid;
            float z[4];
            #pragma unroll
            for (int q = 0; q < 4; ++q) {
                const int c = u + q * 128;
                float s = b0s[c] + x0 * wx0s[c] + x1 * wx0s[G4 + c] + x2 * wx0s[2 * G4 + c];
                #pragma unroll
                for (int gg = 0; gg < 8; ++gg) s += zuA[gg * G4 + c];
                z[q] = s;
            }
            const float ig = sigm(z[0]), fg = sigm(z[1]);
            const float gg = tanhf(z[2]), og = sigm(z[3]);
            const float ch = fg * c0r + ig * gg;
            const float hh = og * tanhf(ch);
            const float k  = tgate(tv, tau0r, s0r);
            const float hn = k * hh + (1.0f - k) * h0r;
            c0r = k * ch + (1.0f - k) * c0r;
            h0r = hn;
            h0s[u] = hn;
            ghu[u] = gr * hn;
            float ssum = hn, qsum = hn * hn;               // one-pass variance
            #pragma unroll
            for (int off = 1; off < 64; off <<= 1) {
                ssum += __shfl_xor(ssum, off);
                qsum += __shfl_xor(qsum, off);
            }
            if ((tid & 63) == 0) {
                red[(tid >> 6) * 2]     = ssum;
                red[(tid >> 6) * 2 + 1] = qsum;
            }
        }
        if (half == 1) {   // h1(t-1) written by wave 0 last iter, crossed B1
            float4 ac = make_float4(0.f, 0.f, 0.f, 0.f);
            {   // rows 0..3: row 0 from register cache pc, rows 1..3 streamed
                const float4 hb = *reinterpret_cast<const float4*>(&hvC[0]);
                ac.x += hb.x * pc.x; ac.y += hb.x * pc.y;
                ac.z += hb.x * pc.z; ac.w += hb.x * pc.w;
                float4 w_;
                w_ = wpC[1 * 128]; ac.x += hb.y*w_.x; ac.y += hb.y*w_.y; ac.z += hb.y*w_.z; ac.w += hb.y*w_.w;
                w_ = wpC[2 * 128]; ac.x += hb.z*w_.x; ac.y += hb.z*w_.y; ac.z += hb.z*w_.z; ac.w += hb.z*w_.w;
                w_ = wpC[3 * 128]; ac.x += hb.w*w_.x; ac.y += hb.w*w_.y; ac.z += hb.w*w_.z; ac.w += hb.w*w_.w;
            }
            #pragma unroll
            for (int i = 4; i < 32; i += 4) {
                const float4 hb = *reinterpret_cast<const float4*>(&hvC[i]);
                ROW4(wpC, i, hb);
            }
            *reinterpret_cast<float4*>(&zuB[(4 + rgC) * G4 + 4 * c4]) = ac;
        }
        __syncthreads();                                   // ===== B2 =====

        // ---- W3: C-half0: Wx1 x gh0(t) -> zuB[0..3] ----
        if (half == 0) {
            float4 ac = make_float4(0.f, 0.f, 0.f, 0.f);
            {
                const float4 hb = *reinterpret_cast<const float4*>(&hvC[0]);
                ac.x += hb.x * pc.x; ac.y += hb.x * pc.y;
                ac.z += hb.x * pc.z; ac.w += hb.x * pc.w;
                float4 w_;
                w_ = wpC[1 * 128]; ac.x += hb.y*w_.x; ac.y += hb.y*w_.y; ac.z += hb.y*w_.z; ac.w += hb.y*w_.w;
                w_ = wpC[2 * 128]; ac.x += hb.z*w_.x; ac.y += hb.z*w_.y; ac.z += hb.z*w_.z; ac.w += hb.z*w_.w;
                w_ = wpC[3 * 128]; ac.x += hb.w*w_.x; ac.y += hb.w*w_.y; ac.z += hb.w*w_.z; ac.w += hb.w*w_.w;
            }
            #pragma unroll
            for (int i = 4; i < 32; i += 4) {
                const float4 hb = *reinterpret_cast<const float4*>(&hvC[i]);
                ROW4(wpC, i, hb);
            }
            *reinterpret_cast<float4*>(&zuB[rgC * G4 + 4 * c4]) = ac;
        }
        __syncthreads();                                   // ===== B3 =====

        // ---- wave 0 only: gates1 (2 units/lane) + FC + softmax; NO barrier.
        //      Other 15 waves roll straight into phase A(t+1); its ~4 kcyc of
        //      port traffic hides this serial tail. Hazards: zuB/red read here,
        //      rewritten only after B1/B2 of t+1 (wave 0 participates in those
        //      barriers, so its reads complete first); ghu[128..] written here,
        //      read by W2(t+1) after B1. ----
        if (wv == 0) {
            const float mu    = (red[0] + red[2]) * (1.0f / 128.0f);
            const float msq   = (red[1] + red[3]) * (1.0f / 128.0f);
            const float rstd  = rsqrtf(msq - mu * mu + 1e-3f);
            const float murstd = mu * rstd;
            float hnv[2];
            #pragma unroll
            for (int e = 0; e < 2; ++e) {
                const int u = lane + e * 64;
                float z[4];
                #pragma unroll
                for (int q = 0; q < 4; ++q) {
                    const int c = u + q * 128;
                    const float sx = (zuB[0*G4+c] + zuB[1*G4+c]) + (zuB[2*G4+c] + zuB[3*G4+c]);
                    const float sh = (zuB[4*G4+c] + zuB[5*G4+c]) + (zuB[6*G4+c] + zuB[7*G4+c]);
                    z[q] = b1s[c] + Ps[c] + rstd * sx - murstd * Qs[c] + sh;
                }
                const float ig = sigm(z[0]), fg = sigm(z[1]);
                const float gg = tanhf(z[2]), og = sigm(z[3]);
                const float cprev = e ? c1B : c1A;
                const float hprev = e ? h1B : h1A;
                const float ch = fg * cprev + ig * gg;
                const float hh = og * tanhf(ch);
                const float k  = tgate(tv, e ? tau1B : tau1A, e ? s1B : s1A);
                const float hn = k * hh + (1.0f - k) * hprev;
                if (e) { c1B = k * ch + (1.0f - k) * c1B; h1B = hn; }
                else   { c1A = k * ch + (1.0f - k) * c1A; h1A = hn; }
                ghu[U + u] = hn;
                hnv[e] = hn;
            }
            // FC + softmax entirely within wave 0
            float p[NCls];
            #pragma unroll
            for (int c = 0; c < NCls; ++c)
                p[c] = hnv[0] * wfcs[lane * 11 + c] + hnv[1] * wfcs[(lane + 64) * 11 + c];
            #pragma unroll
            for (int off = 1; off < 64; off <<= 1) {
                #pragma unroll
                for (int c = 0; c < NCls; ++c) p[c] += __shfl_xor(p[c], off);
            }
            float m = -1e30f;
            #pragma unroll
            for (int c = 0; c < NCls; ++c) { p[c] += bfcs[c]; m = fmaxf(m, p[c]); }
            float ssum = 0.0f;
            #pragma unroll
            for (int c = 0; c < NCls; ++c) { p[c] = __expf(p[c] - m); ssum += p[c]; }
            const float inv = 1.0f / ssum;
            float pv = p[0];               // static-index select (no scratch)
            #pragma unroll
            for (int c = 1; c < NCls; ++c) if (lane == c) pv = p[c];
            if (lane < NCls) op[t * NCls + lane] = pv * inv;
        }
    }
}

extern "C" void kernel_launch(void* const* d_in, const int* in_sizes, int n_in,
                              void* d_out, int out_size, void* d_ws, size_t ws_size,
                              hipStream_t stream) {
    const float* inputs = (const float*)d_in[0];
    const float* times  = (const float*)d_in[1];
    const float* Wx0    = (const float*)d_in[2];
    const float* Wh0    = (const float*)d_in[3];
    const float* b0     = (const float*)d_in[4];
    const float* tau0   = (const float*)d_in[5];
    const float* s0     = (const float*)d_in[6];
    const float* Wx1    = (const float*)d_in[7];
    const float* Wh1    = (const float*)d_in[8];
    const float* b1     = (const float*)d_in[9];
    const float* tau1   = (const float*)d_in[10];
    const float* s1     = (const float*)d_in[11];
    const float* gamma_ = (const float*)d_in[12];
    const float* beta_  = (const float*)d_in[13];
    const float* Wfc    = (const float*)d_in[14];
    const float* bfc    = (const float*)d_in[15];
    float* out = (float*)d_out;

    dim3 grid(BATCH);
    dim3 block(1024);
    hipLaunchKernelGGL(plstm_fused, grid, block, 0, stream,
                       inputs, times, Wx0, Wh0, b0, tau0, s0,
                       Wx1, Wh1, b1, tau1, s1, gamma_, beta_, Wfc, bfc, out);
}

// Round 12
// 23142.647 us; speedup vs baseline: 1.2032x; 1.2032x over previous
//
#include <hip/hip_runtime.h>
#include <math.h>

// Problem constants (fixed by setup_inputs)
constexpr int U      = 128;   // UNITS
constexpr int G4     = 512;   // 4*U gate width
constexpr int NCls   = 10;    // classes
constexpr int TSTEPS = 1000;
constexpr int BATCH  = 256;
constexpr int CROWS  = 48;    // Wh0 rows cached in LDS (96 KB)

// ---------------------------------------------------------------------------
// Evidence ledger:
//  r0 naive per-use loads, 512 thr                15.7 ms
//  r1-r3 cross-barrier register streaming         29-30 ms
//  r4 per-use + 4 accs + LN-fold + 4 barriers      8.57 ms
//  r5 NB=4 batching (grid 64)                     17.1 ms
//  r6 1024 thr + partial-z + packed LDS cache      7.95 ms
//  r7 row-major dwordx4 weight streaming           7.09 ms   <- best
//  r8 16 float4 reg prefetch across barriers      15.5 ms (spill)
//  r9 2-barrier wave-split, gates replicated x4    9.45 ms (replication)
//  r11 r10-structure, demand ~66 > cap 64         27.8 ms (loop-invariant spill:
//      FETCH 43.6 GB / WRITE 111 MB = write-once-read-every-step scratch)
// Laws: (1) VGPR cap = 65536/blockDim (1024thr -> 64); EVERY persistent
//           register must be budgeted; loop-invariants spill first and are
//           re-read every step (catastrophic).
//       (2) Overlap must not replicate work (r9).
// This version = r10 structure with ~11 registers of demand removed:
//   - no pc register cache (stream all C rows)
//   - tau0/s0/tau1/s1/gamma read from staged LDS arrays inside gate phases
// Structure (3 barriers):
//   A: all waves matvec0 -> zuA (48 rows LDS-cached, 80 streamed)
//   B1; W2: tid<128 gates0 || half-1 waves Wh1 x h1(t-1) -> zuB[4..7]
//   B2; W3: half-0 waves Wx1 x gh0(t) -> zuB[0..3]
//   B3; wave 0 ONLY: gates1 (2 units/lane) + FC + softmax + store; NO B4 --
//       the other 15 waves roll into A(t+1), whose ~2.5 kcyc of port work
//       hides wave 0's serial tail.
// ---------------------------------------------------------------------------

__device__ __forceinline__ float sigm(float x) {
    return 1.0f / (1.0f + __expf(-x));
}

// k = time_gate(t, tau, s); floor-mod semantics matching jnp.mod
__device__ __forceinline__ float tgate(float t, float tau, float s) {
    float r = fmodf(t - s, tau);
    if (r < 0.0f) r += tau;
    const float phi = r / tau;
    return (phi < 0.025f) ? 40.0f * phi
         : (phi < 0.05f)  ? 2.0f - 40.0f * phi
         : 0.001f * phi;
}

// 4-row FMA block: ac.{x,y,z,w} are 4 output columns; hb broadcasts 4 rows.
#define ROW4(WP, I, HB) { \
    float4 w_; \
    w_ = (WP)[((I)+0)*128]; ac.x += (HB).x*w_.x; ac.y += (HB).x*w_.y; ac.z += (HB).x*w_.z; ac.w += (HB).x*w_.w; \
    w_ = (WP)[((I)+1)*128]; ac.x += (HB).y*w_.x; ac.y += (HB).y*w_.y; ac.z += (HB).y*w_.z; ac.w += (HB).y*w_.w; \
    w_ = (WP)[((I)+2)*128]; ac.x += (HB).z*w_.x; ac.y += (HB).z*w_.y; ac.z += (HB).z*w_.z; ac.w += (HB).z*w_.w; \
    w_ = (WP)[((I)+3)*128]; ac.x += (HB).w*w_.x; ac.y += (HB).w*w_.y; ac.z += (HB).w*w_.z; ac.w += (HB).w*w_.w; }

__global__ __launch_bounds__(1024, 1) void plstm_fused(
    const float* __restrict__ inputs,  // [B,T,3]
    const float* __restrict__ times,   // [B,T]
    const float* __restrict__ Wx0,     // [3,512]
    const float* __restrict__ Wh0,     // [128,512]
    const float* __restrict__ b0,      // [512]
    const float* __restrict__ tau0,    // [128]
    const float* __restrict__ s0,      // [128]
    const float* __restrict__ Wx1,     // [128,512]
    const float* __restrict__ Wh1,     // [128,512]
    const float* __restrict__ b1,      // [512]
    const float* __restrict__ tau1,    // [128]
    const float* __restrict__ s1,      // [128]
    const float* __restrict__ gamma_,  // [128]
    const float* __restrict__ beta_,   // [128]
    const float* __restrict__ Wfc,     // [128,10]
    const float* __restrict__ bfc,     // [10]
    float* __restrict__ out)           // [B,T,10]
{
    const int tid  = threadIdx.x;       // 0..1023
    const int lane = tid & 63;
    const int wv   = tid >> 6;          // wave 0..15
    const int c4   = tid & 127;         // column quad
    const int g    = tid >> 7;          // phase-A rowgroup 0..7 (16 rows)
    const int half = tid >> 9;          // 0: Wx1 side, 1: Wh1 side (phase C)
    const int rgC  = (tid >> 7) & 3;    // phase-C rowgroup (32 rows)
    const int b    = blockIdx.x;

    __shared__ __align__(16) float wh0c[CROWS * G4];   // 96 KB: Wh0 rows 0..47
    __shared__ __align__(16) float zuA[8 * G4];        // 16 KB layer-0 partials
    __shared__ __align__(16) float zuB[8 * G4];        // 16 KB layer-1 partials
    __shared__ __align__(16) float h0s[U];             // h0 state
    __shared__ __align__(16) float ghu[2 * U];         // [0..127]=gamma*h0, [128..255]=h1
    __shared__ __align__(16) float b0s[G4], b1s[G4], Ps[G4], Qs[G4];
    __shared__ __align__(16) float wx0s[3 * G4];
    __shared__ __align__(16) float wfcs[U * 11];       // stride 11
    __shared__ float tau0s[U], s0s[U], tau1s[U], s1s[U];  // gate params (2 KB)
    __shared__ float bfcs[NCls];
    __shared__ float red[4];                           // {sum0,sq0,sum1,sq1}
    __shared__ float gms[U], bts[U];

    // ---- prologue: stage everything ----
    if (tid < U) {
        gms[tid] = gamma_[tid]; bts[tid] = beta_[tid];
        tau0s[tid] = tau0[tid]; s0s[tid] = s0[tid];
        tau1s[tid] = tau1[tid]; s1s[tid] = s1[tid];
        h0s[tid] = 0.f; ghu[tid] = 0.f; ghu[U + tid] = 0.f;
    }
    {   // Wh0 rows 0..47 contiguous: 6144 float4 = 6 per thread
        float4* dst = reinterpret_cast<float4*>(wh0c);
        const float4* src = reinterpret_cast<const float4*>(Wh0);
        #pragma unroll
        for (int i = 0; i < 6; ++i) dst[tid + i * 1024] = src[tid + i * 1024];
    }
    if (tid < G4) { b0s[tid] = b0[tid]; b1s[tid] = b1[tid]; }
    for (int i = tid; i < 3 * G4; i += 1024) wx0s[i] = Wx0[i];
    for (int i = tid; i < U * NCls; i += 1024) {
        const int u = i / NCls, c = i - u * NCls;
        wfcs[u * 11 + c] = Wfc[i];
    }
    if (tid < NCls) bfcs[tid] = bfc[tid];
    __syncthreads();

    // ---- LN fold constants: P[j]=sum beta[u]*Wx1[u][j], Q[j]=sum gamma[u]*Wx1[u][j]
    if (tid < G4) {
        float P = 0.f, Q = 0.f;
        #pragma unroll 8
        for (int u = 0; u < U; ++u) {
            const float w = Wx1[u * G4 + tid];
            Q += gms[u] * w;
            P += bts[u] * w;
        }
        Ps[tid] = P; Qs[tid] = Q;
    }

    // ---- recurrent state (registers; scalars only, budgeted) ----
    float c0r = 0.f, h0r = 0.f;                       // layer-0 state (tid<128)
    float c1A = 0.f, h1A = 0.f, c1B = 0.f, h1B = 0.f; // layer-1 state (wave 0)

    // ---- loop-invariant bases ----
    const float4* __restrict__ wpA  =
        reinterpret_cast<const float4*>(Wh0) + g * 16 * 128 + c4;       // g>=3 stream
    const float4* __restrict__ wpAc =
        reinterpret_cast<const float4*>(wh0c) + g * 16 * 128 + c4;      // g<3 cached
    const float4* __restrict__ wpC  =
        reinterpret_cast<const float4*>(half ? Wh1 : Wx1) + rgC * 32 * 128 + c4;
    const float* __restrict__ hvC = ghu + half * U + rgC * 32;          // broadcast base

    const float* __restrict__ xp = inputs + (size_t)b * TSTEPS * 3;
    const float* __restrict__ tp = times  + (size_t)b * TSTEPS;
    float*       __restrict__ op = out    + (size_t)b * TSTEPS * NCls;

    float xa0 = xp[0], xa1 = xp[1], xa2 = xp[2], tva = tp[0];

    __syncthreads();

    for (int t = 0; t < TSTEPS; ++t) {
        const float x0 = xa0, x1 = xa1, x2 = xa2, tv = tva;
        const int tn = (t + 1 < TSTEPS) ? t + 1 : t;
        xa0 = xp[tn*3+0]; xa1 = xp[tn*3+1]; xa2 = xp[tn*3+2]; tva = tp[tn];

        // ---- phase A: matvec0 -> zuA (rows g<3 cached, g>=3 streamed) ----
        {
            float4 ac = make_float4(0.f, 0.f, 0.f, 0.f);
            const float4* wp = (g < 3) ? wpAc : wpA;
            #pragma unroll
            for (int i = 0; i < 16; i += 4) {
                const float4 hb = *reinterpret_cast<const float4*>(&h0s[g * 16 + i]);
                ROW4(wp, i, hb);
            }
            *reinterpret_cast<float4*>(&zuA[g * G4 + 4 * c4]) = ac;
        }
        __syncthreads();                                   // ===== B1 =====

        // ---- W2: gates0 (tid<128)  ||  half-1: Wh1 x h1(t-1) -> zuB[4..7] ----
        if (tid < U) {
            const int u = tid;
            float z[4];
            #pragma unroll
            for (int q = 0; q < 4; ++q) {
                const int c = u + q * 128;
                float s = b0s[c] + x0 * wx0s[c] + x1 * wx0s[G4 + c] + x2 * wx0s[2 * G4 + c];
                #pragma unroll
                for (int gg = 0; gg < 8; ++gg) s += zuA[gg * G4 + c];
                z[q] = s;
            }
            const float ig = sigm(z[0]), fg = sigm(z[1]);
            const float gg = tanhf(z[2]), og = sigm(z[3]);
            const float ch = fg * c0r + ig * gg;
            const float hh = og * tanhf(ch);
            const float k  = tgate(tv, tau0s[u], s0s[u]);
            const float hn = k * hh + (1.0f - k) * h0r;
            c0r = k * ch + (1.0f - k) * c0r;
            h0r = hn;
            h0s[u] = hn;
            ghu[u] = gms[u] * hn;
            float ssum = hn, qsum = hn * hn;               // one-pass variance
            #pragma unroll
            for (int off = 1; off < 64; off <<= 1) {
                ssum += __shfl_xor(ssum, off);
                qsum += __shfl_xor(qsum, off);
            }
            if ((tid & 63) == 0) {
                red[(tid >> 6) * 2]     = ssum;
                red[(tid >> 6) * 2 + 1] = qsum;
            }
        }
        if (half == 1) {   // h1(t-1) written by wave 0 before it entered B1
            float4 ac = make_float4(0.f, 0.f, 0.f, 0.f);
            #pragma unroll
            for (int i = 0; i < 32; i += 4) {
                const float4 hb = *reinterpret_cast<const float4*>(&hvC[i]);
                ROW4(wpC, i, hb);
            }
            *reinterpret_cast<float4*>(&zuB[(4 + rgC) * G4 + 4 * c4]) = ac;
        }
        __syncthreads();                                   // ===== B2 =====

        // ---- W3: half-0: Wx1 x gh0(t) -> zuB[0..3] ----
        if (half == 0) {
            float4 ac = make_float4(0.f, 0.f, 0.f, 0.f);
            #pragma unroll
            for (int i = 0; i < 32; i += 4) {
                const float4 hb = *reinterpret_cast<const float4*>(&hvC[i]);
                ROW4(wpC, i, hb);
            }
            *reinterpret_cast<float4*>(&zuB[rgC * G4 + 4 * c4]) = ac;
        }
        __syncthreads();                                   // ===== B3 =====

        // ---- wave 0 only: gates1 (2 units/lane) + FC + softmax; NO barrier.
        //      Hazards: zuB/red read here complete before wave 0 enters
        //      B1(t+1); their next writers run only after B1/B2(t+1).
        //      ghu[128..] written here, before wave 0's B1(t+1); readers
        //      (half-1 W2) read after B1(t+1). ----
        if (wv == 0) {
            const float mu    = (red[0] + red[2]) * (1.0f / 128.0f);
            const float msq   = (red[1] + red[3]) * (1.0f / 128.0f);
            const float rstd  = rsqrtf(msq - mu * mu + 1e-3f);
            const float murstd = mu * rstd;
            float hnv[2];
            #pragma unroll
            for (int e = 0; e < 2; ++e) {
                const int u = lane + e * 64;
                float z[4];
                #pragma unroll
                for (int q = 0; q < 4; ++q) {
                    const int c = u + q * 128;
                    const float sx = (zuB[0*G4+c] + zuB[1*G4+c]) + (zuB[2*G4+c] + zuB[3*G4+c]);
                    const float sh = (zuB[4*G4+c] + zuB[5*G4+c]) + (zuB[6*G4+c] + zuB[7*G4+c]);
                    z[q] = b1s[c] + Ps[c] + rstd * sx - murstd * Qs[c] + sh;
                }
                const float ig = sigm(z[0]), fg = sigm(z[1]);
                const float gg = tanhf(z[2]), og = sigm(z[3]);
                const float cprev = e ? c1B : c1A;
                const float hprev = e ? h1B : h1A;
                const float ch = fg * cprev + ig * gg;
                const float hh = og * tanhf(ch);
                const float k  = tgate(tv, tau1s[u], s1s[u]);
                const float hn = k * hh + (1.0f - k) * hprev;
                if (e) { c1B = k * ch + (1.0f - k) * c1B; h1B = hn; }
                else   { c1A = k * ch + (1.0f - k) * c1A; h1A = hn; }
                ghu[U + u] = hn;
                hnv[e] = hn;
            }
            // FC + softmax entirely within wave 0
            float p[NCls];
            #pragma unroll
            for (int c = 0; c < NCls; ++c)
                p[c] = hnv[0] * wfcs[lane * 11 + c] + hnv[1] * wfcs[(lane + 64) * 11 + c];
            #pragma unroll
            for (int off = 1; off < 64; off <<= 1) {
                #pragma unroll
                for (int c = 0; c < NCls; ++c) p[c] += __shfl_xor(p[c], off);
            }
            float m = -1e30f;
            #pragma unroll
            for (int c = 0; c < NCls; ++c) { p[c] += bfcs[c]; m = fmaxf(m, p[c]); }
            float ssum = 0.0f;
            #pragma unroll
            for (int c = 0; c < NCls; ++c) { p[c] = __expf(p[c] - m); ssum += p[c]; }
            const float inv = 1.0f / ssum;
            float pv = p[0];               // static-index select (no scratch)
            #pragma unroll
            for (int c = 1; c < NCls; ++c) if (lane == c) pv = p[c];
            if (lane < NCls) op[t * NCls + lane] = pv * inv;
        }
    }
}

extern "C" void kernel_launch(void* const* d_in, const int* in_sizes, int n_in,
                              void* d_out, int out_size, void* d_ws, size_t ws_size,
                              hipStream_t stream) {
    const float* inputs = (const float*)d_in[0];
    const float* times  = (const float*)d_in[1];
    const float* Wx0    = (const float*)d_in[2];
    const float* Wh0    = (const float*)d_in[3];
    const float* b0     = (const float*)d_in[4];
    const float* tau0   = (const float*)d_in[5];
    const float* s0     = (const float*)d_in[6];
    const float* Wx1    = (const float*)d_in[7];
    const float* Wh1    = (const float*)d_in[8];
    const float* b1     = (const float*)d_in[9];
    const float* tau1   = (const float*)d_in[10];
    const float* s1     = (const float*)d_in[11];
    const float* gamma_ = (const float*)d_in[12];
    const float* beta_  = (const float*)d_in[13];
    const float* Wfc    = (const float*)d_in[14];
    const float* bfc    = (const float*)d_in[15];
    float* out = (float*)d_out;

    dim3 grid(BATCH);
    dim3 block(1024);
    hipLaunchKernelGGL(plstm_fused, grid, block, 0, stream,
                       inputs, times, Wx0, Wh0, b0, tau0, s0,
                       Wx1, Wh1, b1, tau1, s1, gamma_, beta_, Wfc, bfc, out);
}

// Round 13
// 6842.097 us; speedup vs baseline: 4.0697x; 3.3824x over previous
//
#include <hip/hip_runtime.h>
#include <math.h>

// Problem constants (fixed by setup_inputs)
constexpr int U      = 128;   // UNITS
constexpr int G4     = 512;   // 4*U gate width
constexpr int NCls   = 10;    // classes
constexpr int TSTEPS = 1000;
constexpr int BATCH  = 256;

// ---------------------------------------------------------------------------
// Evidence ledger:
//  r0 naive per-use loads, 512 thr                15.7 ms
//  r1-r3 big register streaming (demand 230)      29-30 ms (spill)
//  r4 per-use + 4 accs + LN-fold, 512 thr          8.57 ms
//  r5 NB=4 batching (grid 64)                     17.1 ms
//  r6 1024 thr + partial-z + packed LDS cache      7.95 ms
//  r7 row-major dwordx4 streaming, 1024 thr        7.09 ms   <- best
//  r8/r11/r12 wave-split structures @1024 thr     15-28 ms (demand > cap 64)
// LAWS: (1) VGPR cap = 65536/blockDim (512thr -> 128, 1024thr -> 64). Demand
//           above cap -> loop-invariants spill to scratch, re-read every step
//           (GB-scale FETCH, catastrophic). Demand BELOW cap is safe even for
//           values held across barriers (r7: 20 scalars, no spill).
//       (2) Overlap must not replicate work (r9).
// This version: 512 threads (cap 128) to BUY register headroom, r7's proven
// 4-barrier skeleton, and a 3-tier Wh0 split + RF phase-C head:
//   phase A (Wh0, 32 rows/group): 12 rows RF (48 VGPR) + 12 rows LDS (96 KB)
//                                 + 8 rows streamed
//   phase C (Wx1|Wh1, 64 rows/group): 4 rows RF (16 VGPR) + 60 streamed
// Streamed bytes/step: 672 -> 544 KB. Register demand ~110 < 128.
// Kill signal: FETCH in GB => RF cache spilled => revert to r7 verbatim.
// ---------------------------------------------------------------------------

__device__ __forceinline__ float sigm(float x) {
    return 1.0f / (1.0f + __expf(-x));
}

// k = time_gate(t, tau, s); floor-mod semantics matching jnp.mod
__device__ __forceinline__ float tgate(float t, float tau, float s) {
    float r = fmodf(t - s, tau);
    if (r < 0.0f) r += tau;
    const float phi = r / tau;
    return (phi < 0.025f) ? 40.0f * phi
         : (phi < 0.05f)  ? 2.0f - 40.0f * phi
         : 0.001f * phi;
}

// 4-row FMA block from a weight POINTER (stride 128 float4 between rows).
#define ROW4(WP, I, HB) { \
    float4 w_; \
    w_ = (WP)[((I)+0)*128]; ac.x += (HB).x*w_.x; ac.y += (HB).x*w_.y; ac.z += (HB).x*w_.z; ac.w += (HB).x*w_.w; \
    w_ = (WP)[((I)+1)*128]; ac.x += (HB).y*w_.x; ac.y += (HB).y*w_.y; ac.z += (HB).y*w_.z; ac.w += (HB).y*w_.w; \
    w_ = (WP)[((I)+2)*128]; ac.x += (HB).z*w_.x; ac.y += (HB).z*w_.y; ac.z += (HB).z*w_.z; ac.w += (HB).z*w_.w; \
    w_ = (WP)[((I)+3)*128]; ac.x += (HB).w*w_.x; ac.y += (HB).w*w_.y; ac.z += (HB).w*w_.z; ac.w += (HB).w*w_.w; }

// 4-row FMA block from 4 REGISTER-cached weight float4s.
#define ROW4P(W0, W1, W2, W3, HB) { \
    ac.x += (HB).x*(W0).x; ac.y += (HB).x*(W0).y; ac.z += (HB).x*(W0).z; ac.w += (HB).x*(W0).w; \
    ac.x += (HB).y*(W1).x; ac.y += (HB).y*(W1).y; ac.z += (HB).y*(W1).z; ac.w += (HB).y*(W1).w; \
    ac.x += (HB).z*(W2).x; ac.y += (HB).z*(W2).y; ac.z += (HB).z*(W2).z; ac.w += (HB).z*(W2).w; \
    ac.x += (HB).w*(W3).x; ac.y += (HB).w*(W3).y; ac.z += (HB).w*(W3).z; ac.w += (HB).w*(W3).w; }

__global__ __launch_bounds__(512, 1) void plstm_fused(
    const float* __restrict__ inputs,  // [B,T,3]
    const float* __restrict__ times,   // [B,T]
    const float* __restrict__ Wx0,     // [3,512]
    const float* __restrict__ Wh0,     // [128,512]
    const float* __restrict__ b0,      // [512]
    const float* __restrict__ tau0,    // [128]
    const float* __restrict__ s0,      // [128]
    const float* __restrict__ Wx1,     // [128,512]
    const float* __restrict__ Wh1,     // [128,512]
    const float* __restrict__ b1,      // [512]
    const float* __restrict__ tau1,    // [128]
    const float* __restrict__ s1,      // [128]
    const float* __restrict__ gamma_,  // [128]
    const float* __restrict__ beta_,   // [128]
    const float* __restrict__ Wfc,     // [128,10]
    const float* __restrict__ bfc,     // [10]
    float* __restrict__ out)           // [B,T,10]
{
    const int tid = threadIdx.x;        // 0..511
    const int c4  = tid & 127;          // column quad (cols 4c4..4c4+3)
    const int g   = tid >> 7;           // rowgroup 0..3
    const int b   = blockIdx.x;

    __shared__ __align__(16) float wh0c[48 * G4];      // 96 KB: 12 rows/group
    __shared__ __align__(16) float zuA[4 * G4];        // 8 KB layer-0 partials
    __shared__ __align__(16) float zuB[4 * G4];        // 8 KB layer-1 partials
    __shared__ __align__(16) float h0s[U];             // h0 state
    __shared__ __align__(16) float ghu[2 * U];         // [0..127]=gamma*h0, [128..255]=h1
    __shared__ __align__(16) float b0s[G4], b1s[G4], Ps[G4], Qs[G4];
    __shared__ __align__(16) float wx0s[3 * G4];
    __shared__ __align__(16) float wfcs[U * 11];       // stride 11
    __shared__ float tau0s[U], s0s[U], tau1s[U], s1s[U];
    __shared__ float bfcs[NCls];
    __shared__ float red[4];                           // {sum0,sq0,sum1,sq1}
    __shared__ float gms[U], bts[U];

    // ---- prologue: stage everything ----
    if (tid < U) {
        gms[tid] = gamma_[tid]; bts[tid] = beta_[tid];
        tau0s[tid] = tau0[tid]; s0s[tid] = s0[tid];
        tau1s[tid] = tau1[tid]; s1s[tid] = s1[tid];
        h0s[tid] = 0.f; ghu[tid] = 0.f; ghu[U + tid] = 0.f;
    }
    {   // wh0c slot s (0..47) <-> Wh0 row 32*(s/12) + 12 + s%12
        float4* dst = reinterpret_cast<float4*>(wh0c);
        #pragma unroll
        for (int i = 0; i < 12; ++i) {
            const int idx  = i * 512 + tid;          // float4 index, 0..6143
            const int slot = idx >> 7;
            const int cq   = idx & 127;
            const int grp  = slot / 12;
            const int row  = 32 * grp + 12 + (slot - grp * 12);
            dst[slot * 128 + cq] =
                *reinterpret_cast<const float4*>(&Wh0[row * G4 + 4 * cq]);
        }
    }
    if (tid < G4) { b0s[tid] = b0[tid]; b1s[tid] = b1[tid]; }
    for (int i = tid; i < 3 * G4; i += 512) wx0s[i] = Wx0[i];
    for (int i = tid; i < U * NCls; i += 512) {
        const int u = i / NCls, c = i - u * NCls;
        wfcs[u * 11 + c] = Wfc[i];
    }
    if (tid < NCls) bfcs[tid] = bfc[tid];
    __syncthreads();

    // ---- LN fold constants: P[j]=sum beta[u]*Wx1[u][j], Q[j]=sum gamma[u]*Wx1[u][j]
    {
        float P = 0.f, Q = 0.f;
        #pragma unroll 8
        for (int u = 0; u < U; ++u) {
            const float w = Wx1[u * G4 + tid];
            Q += gms[u] * w;
            P += bts[u] * w;
        }
        Ps[tid] = P; Qs[tid] = Q;
    }

    // ---- register weight caches (loop-invariant; demand budgeted < 128) ----
    float4 wh0r[12];                        // Wh0 rows 32g..32g+11, my 4 cols
    #pragma unroll
    for (int i = 0; i < 12; ++i)
        wh0r[i] = *reinterpret_cast<const float4*>(&Wh0[(32 * g + i) * G4 + 4 * c4]);
    const float* __restrict__ Wc = (g < 2) ? Wx1 : Wh1;   // phase-C matrix
    const int rb = 64 * (g & 1);                          // phase-C row base
    float4 wcr[4];                          // first 4 C-rows, my 4 cols
    #pragma unroll
    for (int i = 0; i < 4; ++i)
        wcr[i] = *reinterpret_cast<const float4*>(&Wc[(rb + i) * G4 + 4 * c4]);

    // ---- recurrent state (tid<128 only meaningful) ----
    float c0r = 0.f, h0r = 0.f, c1r = 0.f, h1r = 0.f;

    // ---- loop-invariant bases ----
    const float4* __restrict__ wlA =
        reinterpret_cast<const float4*>(wh0c) + (12 * g) * 128 + c4;   // LDS rows
    const float4* __restrict__ wsA =
        reinterpret_cast<const float4*>(Wh0) + (32 * g + 24) * 128 + c4;  // streamed A
    const float4* __restrict__ wsC =
        reinterpret_cast<const float4*>(Wc) + (rb + 4) * 128 + c4;     // streamed C
    const float* __restrict__ hvC = ghu + 64 * g;                      // C broadcast

    const float* __restrict__ xp = inputs + (size_t)b * TSTEPS * 3;
    const float* __restrict__ tp = times  + (size_t)b * TSTEPS;
    float*       __restrict__ op = out    + (size_t)b * TSTEPS * NCls;

    float xa0 = xp[0], xa1 = xp[1], xa2 = xp[2], tva = tp[0];

    __syncthreads();

    for (int t = 0; t < TSTEPS; ++t) {
        const float x0 = xa0, x1 = xa1, x2 = xa2, tv = tva;
        const int tn = (t + 1 < TSTEPS) ? t + 1 : t;
        xa0 = xp[tn*3+0]; xa1 = xp[tn*3+1]; xa2 = xp[tn*3+2]; tva = tp[tn];

        // ---- phase A: matvec0 (12 RF + 12 LDS + 8 streamed rows) -> zuA ----
        {
            float4 ac = make_float4(0.f, 0.f, 0.f, 0.f);
            {   // RF rows 32g..32g+11 (static indices only)
                const float4 hb0 = *reinterpret_cast<const float4*>(&h0s[32 * g + 0]);
                ROW4P(wh0r[0], wh0r[1], wh0r[2], wh0r[3], hb0);
                const float4 hb1 = *reinterpret_cast<const float4*>(&h0s[32 * g + 4]);
                ROW4P(wh0r[4], wh0r[5], wh0r[6], wh0r[7], hb1);
                const float4 hb2 = *reinterpret_cast<const float4*>(&h0s[32 * g + 8]);
                ROW4P(wh0r[8], wh0r[9], wh0r[10], wh0r[11], hb2);
            }
            #pragma unroll
            for (int i = 0; i < 12; i += 4) {   // LDS rows 32g+12..+23
                const float4 hb = *reinterpret_cast<const float4*>(&h0s[32 * g + 12 + i]);
                ROW4(wlA, i, hb);
            }
            #pragma unroll
            for (int i = 0; i < 8; i += 4) {    // streamed rows 32g+24..+31
                const float4 hb = *reinterpret_cast<const float4*>(&h0s[32 * g + 24 + i]);
                ROW4(wsA, i, hb);
            }
            *reinterpret_cast<float4*>(&zuA[g * G4 + 4 * c4]) = ac;
        }
        __syncthreads();                                   // ===== B1 =====

        // ---- gates0 + LN partials (tid < 128) ----
        if (tid < U) {
            const int u = tid;
            float z[4];
            #pragma unroll
            for (int q = 0; q < 4; ++q) {
                const int c = u + q * 128;
                float s = b0s[c] + x0 * wx0s[c] + x1 * wx0s[G4 + c] + x2 * wx0s[2 * G4 + c];
                s += (zuA[c] + zuA[G4 + c]) + (zuA[2 * G4 + c] + zuA[3 * G4 + c]);
                z[q] = s;
            }
            const float ig = sigm(z[0]), fg = sigm(z[1]);
            const float gg = tanhf(z[2]), og = sigm(z[3]);
            const float ch = fg * c0r + ig * gg;
            const float hh = og * tanhf(ch);
            const float k  = tgate(tv, tau0s[u], s0s[u]);
            const float hn = k * hh + (1.0f - k) * h0r;
            c0r = k * ch + (1.0f - k) * c0r;
            h0r = hn;
            h0s[u] = hn;
            ghu[u] = gms[u] * hn;
            float ssum = hn, qsum = hn * hn;               // one-pass variance
            #pragma unroll
            for (int off = 1; off < 64; off <<= 1) {
                ssum += __shfl_xor(ssum, off);
                qsum += __shfl_xor(qsum, off);
            }
            if ((tid & 63) == 0) {
                red[(tid >> 6) * 2]     = ssum;
                red[(tid >> 6) * 2 + 1] = qsum;
            }
        }
        __syncthreads();                                   // ===== B2 =====

        // ---- phase C: matvec1 (4 RF + 60 streamed rows) -> zuB ----
        {
            float4 ac = make_float4(0.f, 0.f, 0.f, 0.f);
            {   // RF rows rb..rb+3
                const float4 hb = *reinterpret_cast<const float4*>(&hvC[0]);
                ROW4P(wcr[0], wcr[1], wcr[2], wcr[3], hb);
            }
            #pragma unroll 5
            for (int i = 0; i < 60; i += 4) {   // streamed rows rb+4..rb+63
                const float4 hb = *reinterpret_cast<const float4*>(&hvC[4 + i]);
                ROW4(wsC, i, hb);
            }
            *reinterpret_cast<float4*>(&zuB[g * G4 + 4 * c4]) = ac;
        }
        __syncthreads();                                   // ===== B3 =====

        // ---- gates1 with LN fold (tid < 128) ----
        if (tid < U) {
            const float mu    = (red[0] + red[2]) * (1.0f / 128.0f);
            const float msq   = (red[1] + red[3]) * (1.0f / 128.0f);
            const float rstd  = rsqrtf(msq - mu * mu + 1e-3f);
            const float murstd = mu * rstd;
            const int u = tid;
            float z[4];
            #pragma unroll
            for (int q = 0; q < 4; ++q) {
                const int c = u + q * 128;
                const float sx = zuB[c] + zuB[G4 + c];              // Wx1 side
                const float sh = zuB[2 * G4 + c] + zuB[3 * G4 + c]; // Wh1 side
                // z1 = b1 + P + rstd*Swx - mu*rstd*Q + Swh (exact LN fold)
                z[q] = b1s[c] + Ps[c] + rstd * sx - murstd * Qs[c] + sh;
            }
            const float ig = sigm(z[0]), fg = sigm(z[1]);
            const float gg = tanhf(z[2]), og = sigm(z[3]);
            const float ch = fg * c1r + ig * gg;
            const float hh = og * tanhf(ch);
            const float k  = tgate(tv, tau1s[u], s1s[u]);
            const float hn = k * hh + (1.0f - k) * h1r;
            c1r = k * ch + (1.0f - k) * c1r;
            h1r = hn;
            ghu[U + u] = hn;                               // h1 state
        }
        __syncthreads();                                   // ===== B4 =====

        // ---- FC + softmax (wave 0); other waves roll into A(t+1) ----
        if (tid < 64) {
            const float a  = ghu[U + tid];
            const float bv = ghu[U + tid + 64];
            float p[NCls];
            #pragma unroll
            for (int c = 0; c < NCls; ++c)
                p[c] = a * wfcs[tid * 11 + c] + bv * wfcs[(tid + 64) * 11 + c];
            #pragma unroll
            for (int off = 1; off < 64; off <<= 1) {
                #pragma unroll
                for (int c = 0; c < NCls; ++c) p[c] += __shfl_xor(p[c], off);
            }
            float m = -1e30f;
            #pragma unroll
            for (int c = 0; c < NCls; ++c) { p[c] += bfcs[c]; m = fmaxf(m, p[c]); }
            float ssum = 0.0f;
            #pragma unroll
            for (int c = 0; c < NCls; ++c) { p[c] = __expf(p[c] - m); ssum += p[c]; }
            const float inv = 1.0f / ssum;
            float pv = p[0];               // static-index select (no scratch)
            #pragma unroll
            for (int c = 1; c < NCls; ++c) if (tid == c) pv = p[c];
            if (tid < NCls) op[t * NCls + tid] = pv * inv;
        }
        // No trailing barrier: A(t+1) writes zuA (last read in gates0 before
        // B2) and reads h0s (written before B2); FC reads ghu[128..]/wfcs,
        // next written in gates1(t+1) behind B1..B3. All hazards fenced.
    }
}

extern "C" void kernel_launch(void* const* d_in, const int* in_sizes, int n_in,
                              void* d_out, int out_size, void* d_ws, size_t ws_size,
                              hipStream_t stream) {
    const float* inputs = (const float*)d_in[0];
    const float* times  = (const float*)d_in[1];
    const float* Wx0    = (const float*)d_in[2];
    const float* Wh0    = (const float*)d_in[3];
    const float* b0     = (const float*)d_in[4];
    const float* tau0   = (const float*)d_in[5];
    const float* s0     = (const float*)d_in[6];
    const float* Wx1    = (const float*)d_in[7];
    const float* Wh1    = (const float*)d_in[8];
    const float* b1     = (const float*)d_in[9];
    const float* tau1   = (const float*)d_in[10];
    const float* s1     = (const float*)d_in[11];
    const float* gamma_ = (const float*)d_in[12];
    const float* beta_  = (const float*)d_in[13];
    const float* Wfc    = (const float*)d_in[14];
    const float* bfc    = (const float*)d_in[15];
    float* out = (float*)d_out;

    dim3 grid(BATCH);
    dim3 block(512);
    hipLaunchKernelGGL(plstm_fused, grid, block, 0, stream,
                       inputs, times, Wx0, Wh0, b0, tau0, s0,
                       Wx1, Wh1, b1, tau1, s1, gamma_, beta_, Wfc, bfc, out);
}